// Round 3
// baseline (2311.797 us; speedup 1.0000x reference)
//
#include <hip/hip_runtime.h>
#include <hip/hip_bf16.h>
#include <cmath>

#define NN 49920
#define EE 200000
#define BB 128

typedef __hip_bfloat16 bf16;

__device__ __forceinline__ float bits2f(unsigned short u) {
    union { unsigned int i; float f; } c; c.i = ((unsigned int)u) << 16; return c.f;
}
__device__ __forceinline__ unsigned short f2bits(float f) {
    union { float f; unsigned int i; } c; c.f = f;
    unsigned int x = c.i;
    return (unsigned short)((x + 0x7fffu + ((x >> 16) & 1u)) >> 16);   // RNE, finite inputs
}

// ---------------- fills ----------------
__global__ void zero_int_kernel(int* __restrict__ p, int n) {
    int i = blockIdx.x * blockDim.x + threadIdx.x;
    if (i < n) p[i] = 0;
}

// ---------------- GEMM: C(bf16) = A@W + bias, 64x64 tile, A dtype templated ----
template<typename TA>
__device__ __forceinline__ float4 loadA4(const TA* p);
template<>
__device__ __forceinline__ float4 loadA4<float>(const float* p) { return *(const float4*)p; }
template<>
__device__ __forceinline__ float4 loadA4<unsigned short>(const unsigned short* p) {
    ushort4 u = *(const ushort4*)p;
    return make_float4(bits2f(u.x), bits2f(u.y), bits2f(u.z), bits2f(u.w));
}

template<typename TA>
__global__ __launch_bounds__(256) void gemm64_kernel(
    const TA* __restrict__ A, const float* __restrict__ W,
    const float* __restrict__ bias, unsigned short* __restrict__ C,
    int M, int K, int N) {
    __shared__ float As[16][65];   // [k][m]
    __shared__ float Bs[16][64];   // [k][n]
    int tid = threadIdx.x;
    int m0 = blockIdx.y * 64, n0 = blockIdx.x * 64;
    int tx = tid & 15, ty = tid >> 4;
    float acc[4][4] = {};

    int ar = tid >> 2;          // 0..63 row in tile
    int ac = (tid & 3) * 4;     // 0,4,8,12 within K-panel
    int bk = tid >> 4;          // 0..15
    int bn = (tid & 15) * 4;    // 0..60

    for (int kk = 0; kk < K; kk += 16) {
        float4 av = loadA4<TA>(&A[(size_t)(m0 + ar) * K + kk + ac]);
        float4 bv = *(const float4*)&W[(size_t)(kk + bk) * N + n0 + bn];
        __syncthreads();
        As[ac + 0][ar] = av.x; As[ac + 1][ar] = av.y;
        As[ac + 2][ar] = av.z; As[ac + 3][ar] = av.w;
        *(float4*)&Bs[bk][bn] = bv;
        __syncthreads();
#pragma unroll
        for (int k = 0; k < 16; k++) {
            float a[4], b[4];
#pragma unroll
            for (int i = 0; i < 4; i++) a[i] = As[k][ty * 4 + i];
#pragma unroll
            for (int j = 0; j < 4; j++) b[j] = Bs[k][tx * 4 + j];
#pragma unroll
            for (int i = 0; i < 4; i++)
#pragma unroll
                for (int j = 0; j < 4; j++) acc[i][j] += a[i] * b[j];
        }
    }
#pragma unroll
    for (int i = 0; i < 4; i++) {
        int m = m0 + ty * 4 + i;
        int n = n0 + tx * 4;
        ushort4 u;
        u.x = f2bits(acc[i][0] + bias[n + 0]);
        u.y = f2bits(acc[i][1] + bias[n + 1]);
        u.z = f2bits(acc[i][2] + bias[n + 2]);
        u.w = f2bits(acc[i][3] + bias[n + 3]);
        *(ushort4*)&C[(size_t)m * N + n] = u;
    }
}

// ---------------- edge scoring: logits only (no atomics) ----------------
template<int HC>
__global__ __launch_bounds__(256) void edge_score_kernel(
    const unsigned short* __restrict__ xl, const unsigned short* __restrict__ xr,
    const float* __restrict__ eattr, const float* __restrict__ We,
    const float* __restrict__ att, const int* __restrict__ ei,
    float* __restrict__ logits, int E) {
    constexpr int J = HC / 256;
    int e = blockIdx.x;
    int tid = threadIdx.x;
    __shared__ float ea[16];
    if (tid < 16) ea[tid] = eattr[(size_t)e * 16 + tid];
    int src = ei[e];
    int dst = ei[E + e];
    __syncthreads();

    int c0 = tid * J;
    float acc[J];
#pragma unroll
    for (int j = 0; j < J; j++) acc[j] = 0.f;
#pragma unroll
    for (int d = 0; d < 16; d++) {
        float a = ea[d];
#pragma unroll
        for (int j = 0; j < J; j++) acc[j] += a * We[d * HC + c0 + j];
    }
    const unsigned short* xls = xl + (size_t)src * HC + c0;
    const unsigned short* xrs = xr + (size_t)dst * HC + c0;
    float part = 0.f;
#pragma unroll
    for (int j = 0; j < J; j++) {
        float v = bits2f(xls[j]) + bits2f(xrs[j]) + acc[j];
        v = v > 0.f ? v : 0.2f * v;
        part += v * att[c0 + j];
    }
#pragma unroll
    for (int off = 32; off > 0; off >>= 1) part += __shfl_down(part, off, 64);
    if ((tid & 63) == 0) {
        int h = tid >> 6;
        logits[(size_t)e * 4 + h] = part;
    }
}

// ---------------- CSR build ----------------
__global__ void hist_kernel(const int* __restrict__ ei, int* __restrict__ counts, int E) {
    int e = blockIdx.x * blockDim.x + threadIdx.x;
    if (e < E) atomicAdd(&counts[ei[E + e]], 1);
}

__global__ __launch_bounds__(1024) void scan_kernel(
    const int* __restrict__ counts, int* __restrict__ offsets,
    int* __restrict__ woff, int N) {
    __shared__ int partial[1024];
    int tid = threadIdx.x;
    const int CH = (N + 1023) >> 10;
    int b0 = tid * CH;
    int s = 0;
    for (int i = 0; i < CH; i++) { int idx = b0 + i; if (idx < N) s += counts[idx]; }
    partial[tid] = s;
    __syncthreads();
    if (tid == 0) {
        int acc = 0;
        for (int i = 0; i < 1024; i++) { int t = partial[i]; partial[i] = acc; acc += t; }
        offsets[N] = acc;
    }
    __syncthreads();
    int run = partial[tid];
    for (int i = 0; i < CH; i++) {
        int idx = b0 + i;
        if (idx < N) { offsets[idx] = run; woff[idx] = run; run += counts[idx]; }
    }
}

__global__ void scatter_kernel(const int* __restrict__ ei, int* __restrict__ woff,
                               int* __restrict__ perm, int E) {
    int e = blockIdx.x * blockDim.x + threadIdx.x;
    if (e < E) {
        int slot = atomicAdd(&woff[ei[E + e]], 1);
        perm[slot] = e;
    }
}

// ---------------- per-node softmax + gather-aggregate + bias + relu ----------
template<int HC, bool OUT_BF16>
__global__ __launch_bounds__(256) void node_agg_kernel(
    const unsigned short* __restrict__ xl, const float* __restrict__ logits,
    const int* __restrict__ ei, const int* __restrict__ offsets,
    const int* __restrict__ perm, const float* __restrict__ bias,
    void* __restrict__ outv, int E) {
    constexpr int K = HC / 256;
    int n = blockIdx.x, tid = threadIdx.x;
    int o0 = offsets[n];
    int deg = offsets[n + 1] - o0;
    __shared__ float s_m[4], s_s[4];

    // phase 1: per-head max & sum(exp); wave w handles head w
    int h = tid >> 6, lane = tid & 63;
    float m = -3.0e38f;
    for (int i = lane; i < deg; i += 64) {
        int e = perm[o0 + i];
        m = fmaxf(m, logits[(size_t)e * 4 + h]);
    }
#pragma unroll
    for (int off = 32; off > 0; off >>= 1) m = fmaxf(m, __shfl_down(m, off, 64));
    m = __shfl(m, 0, 64);
    float s = 0.f;
    for (int i = lane; i < deg; i += 64) {
        int e = perm[o0 + i];
        s += expf(logits[(size_t)e * 4 + h] - m);
    }
#pragma unroll
    for (int off = 32; off > 0; off >>= 1) s += __shfl_down(s, off, 64);
    if (lane == 0) { s_m[h] = m; s_s[h] = s; }
    __syncthreads();

    // phase 2: weighted gather
    float acc[K];
    int c[K], hh[K];
#pragma unroll
    for (int k = 0; k < K; k++) {
        c[k] = tid + k * 256;
        hh[k] = (HC == 1024) ? k : (tid >> 6);
        acc[k] = bias[c[k]];
    }
    for (int i = 0; i < deg; i++) {
        int e = perm[o0 + i];
        int src = ei[e];
        const unsigned short* row = xl + (size_t)src * HC;
#pragma unroll
        for (int k = 0; k < K; k++) {
            float alpha = expf(logits[(size_t)e * 4 + hh[k]] - s_m[hh[k]]) / (s_s[hh[k]] + 1e-16f);
            acc[k] += alpha * bits2f(row[c[k]]);
        }
    }
    if (OUT_BF16) {
        unsigned short* o = (unsigned short*)outv;
#pragma unroll
        for (int k = 0; k < K; k++) {
            float v = acc[k]; v = v > 0.f ? v : 0.f;
            o[(size_t)n * HC + c[k]] = f2bits(v);
        }
    } else {
        float* o = (float*)outv;
#pragma unroll
        for (int k = 0; k < K; k++) {
            float v = acc[k]; v = v > 0.f ? v : 0.f;
            o[(size_t)n * HC + c[k]] = v;
        }
    }
}

// ---------------- master-node indices ----------------
__global__ void compute_last_kernel(const int* __restrict__ n_nodes, int* __restrict__ lastidx, int B) {
    if (blockIdx.x == 0 && threadIdx.x == 0) {
        int s = 0;
        for (int b = 0; b < B; b++) { s += n_nodes[b]; lastidx[b] = s - 1; }
    }
}

// ---------------- MLP head ----------------
__global__ __launch_bounds__(64) void mlp_head_kernel(
    const float* __restrict__ h2, const int* __restrict__ lastidx,
    const float* __restrict__ w1, const float* __restrict__ b1,
    const float* __restrict__ w2, const float* __restrict__ b2,
    float* __restrict__ out) {
    int b = blockIdx.x, tid = threadIdx.x;
    __shared__ float mast[256];
    int node = lastidx[b];
    for (int i = tid; i < 256; i += 64) mast[i] = h2[(size_t)node * 256 + i];
    __syncthreads();
    float z = 0.f;
    for (int k = 0; k < 256; k++) z += mast[k] * w1[k * 64 + tid];
    z += b1[tid];
    z = z > 0.f ? z : 0.f;
    float p = z * w2[tid];
#pragma unroll
    for (int off = 32; off > 0; off >>= 1) p += __shfl_down(p, off, 64);
    if (tid == 0) out[b] = p + b2[0];
}

extern "C" void kernel_launch(void* const* d_in, const int* in_sizes, int n_in,
                              void* d_out, int out_size, void* d_ws, size_t ws_size,
                              hipStream_t stream) {
    const float* x     = (const float*)d_in[0];
    const int*   ei    = (const int*)d_in[1];
    const float* eattr = (const float*)d_in[2];
    const int*   nnod  = (const int*)d_in[3];
    const float* Wl1 = (const float*)d_in[4];
    const float* bl1 = (const float*)d_in[5];
    const float* Wr1 = (const float*)d_in[6];
    const float* br1 = (const float*)d_in[7];
    const float* We1 = (const float*)d_in[8];
    const float* att1= (const float*)d_in[9];
    const float* b1  = (const float*)d_in[10];
    const float* Wl2 = (const float*)d_in[11];
    const float* bl2 = (const float*)d_in[12];
    const float* Wr2 = (const float*)d_in[13];
    const float* br2 = (const float*)d_in[14];
    const float* We2 = (const float*)d_in[15];
    const float* att2= (const float*)d_in[16];
    const float* b2  = (const float*)d_in[17];
    const float* fc1w= (const float*)d_in[18];
    const float* fc1b= (const float*)d_in[19];
    const float* fc2w= (const float*)d_in[20];
    const float* fc2b= (const float*)d_in[21];
    float* out = (float*)d_out;

    const int N = NN, E = EE, B = BB;

    // ---------- workspace layout (peak ~209 MB) ----------
    char* base = (char*)d_ws;
    const size_t NB1 = (size_t)N * 1024 * 2;                  // 102,236,160 B
    // region A [0, NB1): xl1 bf16  | layer2: xl2 bf16 (N*256), xr2 bf16 (N*256), h2 f32 (N*256)
    unsigned short* xl1 = (unsigned short*)base;
    unsigned short* xl2 = (unsigned short*)base;
    unsigned short* xr2 = (unsigned short*)(base + (size_t)N * 256 * 2);
    float*          h2  = (float*)(base + (size_t)N * 256 * 4);
    // region B [NB1, 2*NB1): xr1 bf16 | h1 bf16 overlays xr1 after edge_score1
    unsigned short* xr1 = (unsigned short*)(base + NB1);
    unsigned short* h1  = (unsigned short*)(base + NB1);
    // tail
    char* t = base + 2 * NB1;
    float* logits = (float*)t;      t += (size_t)E * 4 * sizeof(float);
    int* counts   = (int*)t;        t += (size_t)N * sizeof(int);
    int* offsets  = (int*)t;        t += (size_t)(N + 1) * sizeof(int);
    int* woff     = (int*)t;        t += (size_t)N * sizeof(int);
    int* perm     = (int*)t;        t += (size_t)E * sizeof(int);
    int* lastidx  = (int*)t;        t += (size_t)B * sizeof(int);
    size_t required = (size_t)(t - base);
    if (ws_size < required) return;   // guard: signals ws shortage as absmax-fail, not abort

    dim3 blk(256);

    // ---------- CSR build (depends only on edge_index; shared by both layers) ----------
    zero_int_kernel<<<(N + 255) / 256, blk, 0, stream>>>(counts, N);
    hist_kernel<<<(E + 255) / 256, blk, 0, stream>>>(ei, counts, E);
    scan_kernel<<<1, 1024, 0, stream>>>(counts, offsets, woff, N);
    scatter_kernel<<<(E + 255) / 256, blk, 0, stream>>>(ei, woff, perm, E);

    // ---------- layer 1 ----------
    {
        dim3 g1(1024 / 64, N / 64);
        gemm64_kernel<float><<<g1, blk, 0, stream>>>(x, Wl1, bl1, xl1, N, 128, 1024);
        gemm64_kernel<float><<<g1, blk, 0, stream>>>(x, Wr1, br1, xr1, N, 128, 1024);
    }
    edge_score_kernel<1024><<<E, blk, 0, stream>>>(xl1, xr1, eattr, We1, att1, ei, logits, E);
    node_agg_kernel<1024, true><<<N, blk, 0, stream>>>(xl1, logits, ei, offsets, perm, b1, h1, E);

    // ---------- layer 2 ----------
    {
        dim3 g2(256 / 64, N / 64);
        gemm64_kernel<unsigned short><<<g2, blk, 0, stream>>>(h1, Wl2, bl2, xl2, N, 1024, 256);
        gemm64_kernel<unsigned short><<<g2, blk, 0, stream>>>(h1, Wr2, br2, xr2, N, 1024, 256);
    }
    edge_score_kernel<256><<<E, blk, 0, stream>>>(xl2, xr2, eattr, We2, att2, ei, logits, E);
    node_agg_kernel<256, false><<<N, blk, 0, stream>>>(xl2, logits, ei, offsets, perm, b2, h2, E);

    // ---------- head ----------
    compute_last_kernel<<<1, 64, 0, stream>>>(nnod, lastidx, B);
    mlp_head_kernel<<<B, 64, 0, stream>>>(h2, lastidx, fc1w, fc1b, fc2w, fc2b, out);
}

// Round 4
// 1298.269 us; speedup vs baseline: 1.7807x; 1.7807x over previous
//
#include <hip/hip_runtime.h>
#include <hip/hip_bf16.h>
#include <cmath>

#define NN 49920
#define EE 200000
#define BB 128

typedef __attribute__((ext_vector_type(8))) short short8;
typedef __attribute__((ext_vector_type(4))) float floatx4;

__device__ __forceinline__ float bits2f(unsigned short u) {
    union { unsigned int i; float f; } c; c.i = ((unsigned int)u) << 16; return c.f;
}
__device__ __forceinline__ unsigned short f2bits(float f) {
    union { float f; unsigned int i; } c; c.f = f;
    unsigned int x = c.i;
    return (unsigned short)((x + 0x7fffu + ((x >> 16) & 1u)) >> 16);   // RNE, finite inputs
}

// ---------------- small utility kernels ----------------
__global__ void zero_int_kernel(int* __restrict__ p, int n) {
    int i = blockIdx.x * blockDim.x + threadIdx.x;
    if (i < n) p[i] = 0;
}

__global__ void convert_bf16_kernel(const float* __restrict__ src, unsigned short* __restrict__ dst, int n) {
    int i = blockIdx.x * blockDim.x + threadIdx.x;
    if (i < n) dst[i] = f2bits(src[i]);
}

// ---------------- bf16 MFMA GEMM: C(bf16) = A@W + bias ----------------
// A [M,K] bf16 row-major, W [K,N] bf16 row-major, bias [N] f32, C [M,N] bf16.
// Block: 256 thr = 4 waves, 128x128 C-tile (waves 2x2 of 64x64), BK=32.
#define LDK 40   // padded LDS k-stride in ushorts (80B: keeps b128 16B-aligned, 2-way banks)

__global__ __launch_bounds__(256) void mfma_gemm_kernel(
    const unsigned short* __restrict__ A, const unsigned short* __restrict__ W,
    const float* __restrict__ bias, unsigned short* __restrict__ C,
    int M, int K, int N) {
    __shared__ unsigned short As[128 * LDK];
    __shared__ unsigned short Bt[128 * LDK];   // B transposed: Bt[n][k]
    int tid = threadIdx.x;
    int lane = tid & 63, wid = tid >> 6;
    int gm0 = blockIdx.y * 128, gn0 = blockIdx.x * 128;
    int wm = (wid & 1) * 64, wn = (wid >> 1) * 64;
    int row15 = lane & 15, quad = lane >> 4;

    floatx4 acc[4][4];
#pragma unroll
    for (int i = 0; i < 4; i++)
#pragma unroll
        for (int j = 0; j < 4; j++)
#pragma unroll
            for (int r = 0; r < 4; r++) acc[i][j][r] = 0.f;

    for (int k0 = 0; k0 < K; k0 += 32) {
        __syncthreads();
        // stage A: 128 rows x 32 k (bf16), k-contiguous
        {
            int idx = tid;
#pragma unroll
            for (int l = 0; l < 2; l++, idx += 256) {
                int r = idx >> 2;           // 0..127
                int kp = (idx & 3) * 8;     // 0,8,16,24
                *(uint4*)&As[r * LDK + kp] = *(const uint4*)&A[(size_t)(gm0 + r) * K + k0 + kp];
            }
        }
        // stage B with transpose: W[k][n] -> Bt[n][k]
        {
            int idx = tid;
#pragma unroll
            for (int l = 0; l < 2; l++, idx += 256) {
                int kr = idx >> 4;           // 0..31
                int cg = (idx & 15) * 8;     // 0..120
                union { uint4 v; unsigned short u[8]; } w;
                w.v = *(const uint4*)&W[(size_t)(k0 + kr) * N + gn0 + cg];
#pragma unroll
                for (int j = 0; j < 8; j++) Bt[(cg + j) * LDK + kr] = w.u[j];
            }
        }
        __syncthreads();
        short8 af[4], bfr[4];
#pragma unroll
        for (int i = 0; i < 4; i++)
            af[i] = *(const short8*)&As[(wm + 16 * i + row15) * LDK + quad * 8];
#pragma unroll
        for (int j = 0; j < 4; j++)
            bfr[j] = *(const short8*)&Bt[(wn + 16 * j + row15) * LDK + quad * 8];
#pragma unroll
        for (int i = 0; i < 4; i++)
#pragma unroll
            for (int j = 0; j < 4; j++)
                acc[i][j] = __builtin_amdgcn_mfma_f32_16x16x32_bf16(af[i], bfr[j], acc[i][j], 0, 0, 0);
    }

    // epilogue: C[row][col], row=(quad*4+r)+16i+wm, col=row15+16j+wn
    int colb = gn0 + wn + row15;
#pragma unroll
    for (int i = 0; i < 4; i++) {
#pragma unroll
        for (int j = 0; j < 4; j++) {
            int col = colb + 16 * j;
            float bv = bias[col];
#pragma unroll
            for (int r = 0; r < 4; r++) {
                int rrow = gm0 + wm + 16 * i + quad * 4 + r;
                C[(size_t)rrow * N + col] = f2bits(acc[i][j][r] + bv);
            }
        }
    }
}

// ---------------- edge scoring: We in registers, 32 edges/block ----------------
template<int HC>
__global__ __launch_bounds__(256) void edge_score_kernel(
    const unsigned short* __restrict__ xl, const unsigned short* __restrict__ xr,
    const float* __restrict__ eattr, const float* __restrict__ We,
    const float* __restrict__ att, const int* __restrict__ ei,
    float* __restrict__ logits, int E) {
    constexpr int J = HC / 256;
    constexpr int EB = 32;
    __shared__ float ea_s[EB][16];
    __shared__ int src_s[EB], dst_s[EB];
    int tid = threadIdx.x;
    int e0 = blockIdx.x * EB;

    for (int t = tid; t < EB * 16; t += 256) ea_s[t >> 4][t & 15] = eattr[(size_t)e0 * 16 + t];
    if (tid < EB) { src_s[tid] = ei[e0 + tid]; dst_s[tid] = ei[E + e0 + tid]; }
    __syncthreads();

    int c0 = tid * J;
    float Wreg[16 * J];
#pragma unroll
    for (int d = 0; d < 16; d++)
#pragma unroll
        for (int j = 0; j < J; j++) Wreg[d * J + j] = We[d * HC + c0 + j];
    float att_r[J];
#pragma unroll
    for (int j = 0; j < J; j++) att_r[j] = att[c0 + j];

    int h = tid >> 6;
    for (int ee = 0; ee < EB; ee++) {
        int src = src_s[ee], dst = dst_s[ee];
        float ef[J];
#pragma unroll
        for (int j = 0; j < J; j++) ef[j] = 0.f;
#pragma unroll
        for (int d = 0; d < 16; d++) {
            float a = ea_s[ee][d];
#pragma unroll
            for (int j = 0; j < J; j++) ef[j] += a * Wreg[d * J + j];
        }
        unsigned short us_l[J], us_r[J];
        if (J == 4) {
            *(ushort4*)us_l = *(const ushort4*)&xl[(size_t)src * HC + c0];
            *(ushort4*)us_r = *(const ushort4*)&xr[(size_t)dst * HC + c0];
        } else {
            us_l[0] = xl[(size_t)src * HC + c0];
            us_r[0] = xr[(size_t)dst * HC + c0];
        }
        float part = 0.f;
#pragma unroll
        for (int j = 0; j < J; j++) {
            float v = bits2f(us_l[j]) + bits2f(us_r[j]) + ef[j];
            v = v > 0.f ? v : 0.2f * v;
            part += v * att_r[j];
        }
#pragma unroll
        for (int off = 32; off > 0; off >>= 1) part += __shfl_down(part, off, 64);
        if ((tid & 63) == 0) logits[(size_t)(e0 + ee) * 4 + h] = part;
    }
}

// ---------------- CSR build ----------------
__global__ void hist_kernel(const int* __restrict__ ei, int* __restrict__ counts, int E) {
    int e = blockIdx.x * blockDim.x + threadIdx.x;
    if (e < E) atomicAdd(&counts[ei[E + e]], 1);
}

__global__ __launch_bounds__(1024) void scan_kernel(
    const int* __restrict__ counts, int* __restrict__ offsets,
    int* __restrict__ woff, int N) {
    __shared__ int partial[1024];
    int tid = threadIdx.x;
    const int CH = (N + 1023) >> 10;
    int b0 = tid * CH;
    int s = 0;
    for (int i = 0; i < CH; i++) { int idx = b0 + i; if (idx < N) s += counts[idx]; }
    partial[tid] = s;
    __syncthreads();
    if (tid == 0) {
        int acc = 0;
        for (int i = 0; i < 1024; i++) { int t = partial[i]; partial[i] = acc; acc += t; }
        offsets[N] = acc;
    }
    __syncthreads();
    int run = partial[tid];
    for (int i = 0; i < CH; i++) {
        int idx = b0 + i;
        if (idx < N) { offsets[idx] = run; woff[idx] = run; run += counts[idx]; }
    }
}

__global__ void scatter_kernel(const int* __restrict__ ei, int* __restrict__ woff,
                               int* __restrict__ perm, int E) {
    int e = blockIdx.x * blockDim.x + threadIdx.x;
    if (e < E) {
        int slot = atomicAdd(&woff[ei[E + e]], 1);
        perm[slot] = e;
    }
}

// ---------------- per-node softmax + gather-aggregate + bias + relu ----------
template<int HC, bool OUT_BF16>
__global__ __launch_bounds__(256) void node_agg_kernel(
    const unsigned short* __restrict__ xl, const float* __restrict__ logits,
    const int* __restrict__ ei, const int* __restrict__ offsets,
    const int* __restrict__ perm, const float* __restrict__ bias,
    void* __restrict__ outv, int E) {
    constexpr int V = HC / 256;   // 4 or 1
    int n = blockIdx.x, tid = threadIdx.x;
    int o0 = offsets[n];
    int deg = offsets[n + 1] - o0;
    __shared__ float s_m[4], s_s[4];
    int h = tid >> 6, lane = tid & 63;

    // phase 1: per-head max & sum(exp); wave w handles head w
    float m = -3.0e38f;
    for (int i = lane; i < deg; i += 64) {
        int e = perm[o0 + i];
        m = fmaxf(m, logits[(size_t)e * 4 + h]);
    }
#pragma unroll
    for (int off = 32; off > 0; off >>= 1) m = fmaxf(m, __shfl_down(m, off, 64));
    m = __shfl(m, 0, 64);
    float s = 0.f;
    for (int i = lane; i < deg; i += 64) {
        int e = perm[o0 + i];
        s += expf(logits[(size_t)e * 4 + h] - m);
    }
#pragma unroll
    for (int off = 32; off > 0; off >>= 1) s += __shfl_down(s, off, 64);
    if (lane == 0) { s_m[h] = m; s_s[h] = s; }
    __syncthreads();

    float mh = s_m[h];
    float inv = 1.f / (s_s[h] + 1e-16f);
    int c0 = tid * V;
    float acc[V];
#pragma unroll
    for (int v = 0; v < V; v++) acc[v] = bias[c0 + v];

    for (int i = 0; i < deg; i++) {
        int e = perm[o0 + i];
        int src = ei[e];
        float alpha = expf(logits[(size_t)e * 4 + h] - mh) * inv;
        unsigned short us[V];
        if (V == 4) *(ushort4*)us = *(const ushort4*)&xl[(size_t)src * HC + c0];
        else us[0] = xl[(size_t)src * HC + c0];
#pragma unroll
        for (int v = 0; v < V; v++) acc[v] += alpha * bits2f(us[v]);
    }

    if (OUT_BF16) {
        unsigned short* o = (unsigned short*)outv;
        if (V == 4) {
            ushort4 u;
            u.x = f2bits(fmaxf(acc[0], 0.f));
            u.y = f2bits(fmaxf(acc[1], 0.f));
            u.z = f2bits(fmaxf(acc[2], 0.f));
            u.w = f2bits(fmaxf(acc[3], 0.f));
            *(ushort4*)&o[(size_t)n * HC + c0] = u;
        } else {
            o[(size_t)n * HC + c0] = f2bits(fmaxf(acc[0], 0.f));
        }
    } else {
        float* o = (float*)outv;
#pragma unroll
        for (int v = 0; v < V; v++) o[(size_t)n * HC + c0 + v] = fmaxf(acc[v], 0.f);
    }
}

// ---------------- master-node indices ----------------
__global__ void compute_last_kernel(const int* __restrict__ n_nodes, int* __restrict__ lastidx, int B) {
    if (blockIdx.x == 0 && threadIdx.x == 0) {
        int s = 0;
        for (int b = 0; b < B; b++) { s += n_nodes[b]; lastidx[b] = s - 1; }
    }
}

// ---------------- MLP head ----------------
__global__ __launch_bounds__(64) void mlp_head_kernel(
    const float* __restrict__ h2, const int* __restrict__ lastidx,
    const float* __restrict__ w1, const float* __restrict__ b1,
    const float* __restrict__ w2, const float* __restrict__ b2,
    float* __restrict__ out) {
    int b = blockIdx.x, tid = threadIdx.x;
    __shared__ float mast[256];
    int node = lastidx[b];
    for (int i = tid; i < 256; i += 64) mast[i] = h2[(size_t)node * 256 + i];
    __syncthreads();
    float z = 0.f;
    for (int k = 0; k < 256; k++) z += mast[k] * w1[k * 64 + tid];
    z += b1[tid];
    z = z > 0.f ? z : 0.f;
    float p = z * w2[tid];
#pragma unroll
    for (int off = 32; off > 0; off >>= 1) p += __shfl_down(p, off, 64);
    if (tid == 0) out[b] = p + b2[0];
}

extern "C" void kernel_launch(void* const* d_in, const int* in_sizes, int n_in,
                              void* d_out, int out_size, void* d_ws, size_t ws_size,
                              hipStream_t stream) {
    const float* x     = (const float*)d_in[0];
    const int*   ei    = (const int*)d_in[1];
    const float* eattr = (const float*)d_in[2];
    const int*   nnod  = (const int*)d_in[3];
    const float* Wl1 = (const float*)d_in[4];
    const float* bl1 = (const float*)d_in[5];
    const float* Wr1 = (const float*)d_in[6];
    const float* br1 = (const float*)d_in[7];
    const float* We1 = (const float*)d_in[8];
    const float* att1= (const float*)d_in[9];
    const float* b1  = (const float*)d_in[10];
    const float* Wl2 = (const float*)d_in[11];
    const float* bl2 = (const float*)d_in[12];
    const float* Wr2 = (const float*)d_in[13];
    const float* br2 = (const float*)d_in[14];
    const float* We2 = (const float*)d_in[15];
    const float* att2= (const float*)d_in[16];
    const float* b2  = (const float*)d_in[17];
    const float* fc1w= (const float*)d_in[18];
    const float* fc1b= (const float*)d_in[19];
    const float* fc2w= (const float*)d_in[20];
    const float* fc2b= (const float*)d_in[21];
    float* out = (float*)d_out;

    const int N = NN, E = EE, B = BB;

    // ---------- workspace layout (peak ~224 MB) ----------
    char* base = (char*)d_ws;
    const size_t NB1 = (size_t)N * 1024 * 2;                  // 102,236,160 B
    // region A [0, NB1): xl1 bf16  | layer2: xl2 bf16 (N*256), xr2 bf16 (N*256), h2 f32 (N*256)
    unsigned short* xl1 = (unsigned short*)base;
    unsigned short* xl2 = (unsigned short*)base;
    unsigned short* xr2 = (unsigned short*)(base + (size_t)N * 256 * 2);
    float*          h2  = (float*)(base + (size_t)N * 256 * 4);
    // region B [NB1, 2*NB1): xr1 bf16 | h1 bf16 overlays xr1 after edge_score1
    unsigned short* xr1 = (unsigned short*)(base + NB1);
    unsigned short* h1  = (unsigned short*)(base + NB1);
    // tail
    char* t = base + 2 * NB1;
    float* logits = (float*)t;        t += (size_t)E * 4 * sizeof(float);
    int* counts   = (int*)t;          t += (size_t)N * sizeof(int);
    int* offsets  = (int*)t;          t += (size_t)(N + 1) * sizeof(int);
    int* woff     = (int*)t;          t += (size_t)N * sizeof(int);
    int* perm     = (int*)t;          t += (size_t)E * sizeof(int);
    int* lastidx  = (int*)t;          t += 64 * sizeof(int);  // B=128 ints -> pad to 64*4*?; keep simple
    t += (size_t)B * sizeof(int);
    unsigned short* xb   = (unsigned short*)t; t += (size_t)N * 128 * 2;
    unsigned short* wl1b = (unsigned short*)t; t += (size_t)128 * 1024 * 2;
    unsigned short* wr1b = (unsigned short*)t; t += (size_t)128 * 1024 * 2;
    unsigned short* wl2b = (unsigned short*)t; t += (size_t)1024 * 256 * 2;
    unsigned short* wr2b = (unsigned short*)t; t += (size_t)1024 * 256 * 2;
    size_t required = (size_t)(t - base);
    if (ws_size < required) return;   // guard: absmax-fail instead of abort

    dim3 blk(256);

    // ---------- CSR build ----------
    zero_int_kernel<<<(N + 255) / 256, blk, 0, stream>>>(counts, N);
    hist_kernel<<<(E + 255) / 256, blk, 0, stream>>>(ei, counts, E);
    scan_kernel<<<1, 1024, 0, stream>>>(counts, offsets, woff, N);
    scatter_kernel<<<(E + 255) / 256, blk, 0, stream>>>(ei, woff, perm, E);

    // ---------- bf16 conversions ----------
    convert_bf16_kernel<<<(N * 128 + 255) / 256, blk, 0, stream>>>(x, xb, N * 128);
    convert_bf16_kernel<<<(128 * 1024 + 255) / 256, blk, 0, stream>>>(Wl1, wl1b, 128 * 1024);
    convert_bf16_kernel<<<(128 * 1024 + 255) / 256, blk, 0, stream>>>(Wr1, wr1b, 128 * 1024);
    convert_bf16_kernel<<<(1024 * 256 + 255) / 256, blk, 0, stream>>>(Wl2, wl2b, 1024 * 256);
    convert_bf16_kernel<<<(1024 * 256 + 255) / 256, blk, 0, stream>>>(Wr2, wr2b, 1024 * 256);

    // ---------- layer 1 ----------
    {
        dim3 g1(1024 / 128, N / 128);
        mfma_gemm_kernel<<<g1, blk, 0, stream>>>(xb, wl1b, bl1, xl1, N, 128, 1024);
        mfma_gemm_kernel<<<g1, blk, 0, stream>>>(xb, wr1b, br1, xr1, N, 128, 1024);
    }
    edge_score_kernel<1024><<<E / 32, blk, 0, stream>>>(xl1, xr1, eattr, We1, att1, ei, logits, E);
    node_agg_kernel<1024, true><<<N, blk, 0, stream>>>(xl1, logits, ei, offsets, perm, b1, h1, E);

    // ---------- layer 2 ----------
    {
        dim3 g2(256 / 128, N / 128);
        mfma_gemm_kernel<<<g2, blk, 0, stream>>>(h1, wl2b, bl2, xl2, N, 1024, 256);
        mfma_gemm_kernel<<<g2, blk, 0, stream>>>(h1, wr2b, br2, xr2, N, 1024, 256);
    }
    edge_score_kernel<256><<<E / 32, blk, 0, stream>>>(xl2, xr2, eattr, We2, att2, ei, logits, E);
    node_agg_kernel<256, false><<<N, blk, 0, stream>>>(xl2, logits, ei, offsets, perm, b2, h2, E);

    // ---------- head ----------
    compute_last_kernel<<<1, 64, 0, stream>>>(nnod, lastidx, B);
    mlp_head_kernel<<<B, 64, 0, stream>>>(h2, lastidx, fc1w, fc1b, fc2w, fc2b, out);
}